// Round 7
// baseline (434.660 us; speedup 1.0000x reference)
//
#include <hip/hip_runtime.h>
#include <stdint.h>

typedef unsigned short u16;
typedef __bf16 bf16x8 __attribute__((ext_vector_type(8)));
typedef float floatx4 __attribute__((ext_vector_type(4)));

#define AS1(p) ((__attribute__((address_space(1))) void*)(void*)(p))
#define AS3(p) ((__attribute__((address_space(3))) void*)(p))

__device__ __forceinline__ u16 f2bf(float f) {
    unsigned u;
    __builtin_memcpy(&u, &f, 4);
    u += 0x7FFF + ((u >> 16) & 1);   // RNE
    return (u16)(u >> 16);
}
__device__ __forceinline__ u16 f2bf_trunc(float f) {
    unsigned u;
    __builtin_memcpy(&u, &f, 4);
    return (u16)(u >> 16);
}
__device__ __forceinline__ float exp2_fast(float x) {
    return __builtin_amdgcn_exp2f(x);    // v_exp_f32
}
__device__ __forceinline__ float gelu_f(float x) {
    return 0.5f * x * (1.0f + erff(x * 0.70710678118654752f));
}

// ---------------------------------------------------------------------------
// Convert the 6 weight matrices fp32 -> bf16 into ws (layout: wq wk wv wo f1 f2)
// ---------------------------------------------------------------------------
__global__ __launch_bounds__(256) void conv_w_kernel(
    const float* __restrict__ wq, const float* __restrict__ wk,
    const float* __restrict__ wv, const float* __restrict__ wo,
    const float* __restrict__ f1, const float* __restrict__ f2,
    const float* __restrict__ bq, const float* __restrict__ bk,
    const float* __restrict__ bv, float* __restrict__ qkvb,
    u16* __restrict__ W) {
    const size_t i4 = ((size_t)blockIdx.x * 256 + threadIdx.x) * 4;
    const size_t M1 = 1048576;
    const float* src;
    size_t off;
    if (i4 < M1)            { src = wq; off = i4; }
    else if (i4 < 2 * M1)   { src = wk; off = i4 - M1; }
    else if (i4 < 3 * M1)   { src = wv; off = i4 - 2 * M1; }
    else if (i4 < 4 * M1)   { src = wo; off = i4 - 3 * M1; }
    else if (i4 < 8 * M1)   { src = f1; off = i4 - 4 * M1; }
    else                    { src = f2; off = i4 - 8 * M1; }
    float4 d = *(const float4*)(src + off);
    ushort4 o;
    o.x = f2bf(d.x); o.y = f2bf(d.y); o.z = f2bf(d.z); o.w = f2bf(d.w);
    *(ushort4*)(W + i4) = o;
    if (blockIdx.x == 0) {
        for (int i = threadIdx.x; i < 1024; i += 256) {
            qkvb[i] = bq[i];
            qkvb[1024 + i] = bk[i];
            qkvb[2048 + i] = bv[i];
        }
    }
}

// ---------------------------------------------------------------------------
// LayerNorm: one wave per token row (D=1024 -> 16 elems/lane). fp32 in, bf16 out.
// ---------------------------------------------------------------------------
__global__ __launch_bounds__(64) void ln_kernel(const float* __restrict__ X,
                                                const float* __restrict__ G,
                                                const float* __restrict__ Bt,
                                                u16* __restrict__ Y) {
    const int row = blockIdx.x;
    const int lane = threadIdx.x;
    const float* xr = X + (size_t)row * 1024;
    float v[16];
    float s = 0.f;
#pragma unroll
    for (int i = 0; i < 16; ++i) { v[i] = xr[lane + i * 64]; s += v[i]; }
#pragma unroll
    for (int off = 1; off < 64; off <<= 1) s += __shfl_xor(s, off, 64);
    const float mu = s * (1.0f / 1024.0f);
    float ss = 0.f;
#pragma unroll
    for (int i = 0; i < 16; ++i) { float d = v[i] - mu; ss += d * d; }
#pragma unroll
    for (int off = 1; off < 64; off <<= 1) ss += __shfl_xor(ss, off, 64);
    const float rstd = rsqrtf(ss * (1.0f / 1024.0f) + 1e-5f);
    u16* yr = Y + (size_t)row * 1024;
#pragma unroll
    for (int i = 0; i < 16; ++i) {
        int c = lane + i * 64;
        yr[c] = f2bf((v[i] - mu) * rstd * G[c] + Bt[c]);
    }
}

// ---------------------------------------------------------------------------
// gemm128p: 128x128 tile, 4 waves (2Mx2N, 64x64 each), BK=64, 256 threads
// (1 wave/SIMD -> 512-reg budget, no occupancy cliff). Used for ALL GEMMs.
//
// Two-level pipeline:
//  - LDS: 4 buffers, staged 3 tiles ahead (proven gemm128sq skeleton).
//    Per-tile end-sync: STG(T+3); vmcnt(8) [retires T+2; T+3 stays in
//    flight]; s_barrier. Entry invariant: tiles T,T+1 valid & crossed.
//  - Registers: counted-lgkm operand double-buffer. Slice regs s0/s1
//    (8 x bf16x8 each). Body:
//      issue reads (T,kk1)->s1            [lgkm: 8 old + 8 new]
//      lgkmcnt(8)  -> s0=(T,kk0) ready;   MFMA kk0 (16) covers s1 delivery
//      issue reads (T+1,kk0)->s0          [T+1 LDS valid per invariant]
//      STG(T+3)                           [buf (T-1)&3: readers retired at
//                                          iter T-1's lgkm before its BAR]
//      lgkmcnt(8|0) -> s1 ready;          MFMA kk1 (16) covers T+1 delivery
//    Steady-state exposed LDS wait ~0; ONE barrier per K-tile.
// T2 XOR-swizzle via inverse-swizzled global source + linear global_load_lds
// dest + swizzled ds_read (rule #21). Grid (M/128, N/128). 128 KiB dyn LDS.
// Epilogue: out = [gelu](A@Bt^T + bias) [+ resid], fp32 or bf16.
// ---------------------------------------------------------------------------
__global__ __launch_bounds__(256, 1) void gemm128p_kernel(
    const u16* __restrict__ A, const u16* __restrict__ Bt,
    const float* __restrict__ bias, const float* __restrict__ resid,
    void* __restrict__ Cp, int M, int N, int K, int act, int c_f32) {
    extern __shared__ __align__(16) u16 smem[];   // 4 bufs x (A 16KB + B 16KB)
    const int tid = threadIdx.x;
    const int wave = tid >> 6, lane = tid & 63;
    const int wm = (wave >> 1) * 64;
    const int wn = (wave & 1) * 64;
    const int lr = lane & 15, lk8 = (lane >> 4) * 8;
    const int r0 = (lane >> 4) * 4;
    const int m0 = blockIdx.x * 128, n0 = blockIdx.y * 128;
    const int NT = K >> 6;                        // 16 or 64 (>= 4)
    const u16* const Ab = A + (size_t)m0 * K;
    const u16* const Bb = Bt + (size_t)n0 * K;

    // staging: linear LDS dest, inverse-swizzled global source column
    const int srow = tid >> 3;                    // 0..31
    const int scol = 8 * ((tid & 7) ^ (srow & 7));
    const int sdst = tid * 8;                     // u16 offset within 2048-u16 chunk
    // read-side swizzle: elem col c at LDS row R -> c ^ ((R&7)<<3); R&7 == lr&7
    const int swz = (lr & 7) << 3;
    const int c0 = lk8 ^ swz;                     // kk=0 fragment column
    const int c1 = (32 + lk8) ^ swz;              // kk=1 fragment column

    floatx4 acc[4][4];
#pragma unroll
    for (int i = 0; i < 4; ++i)
#pragma unroll
        for (int j = 0; j < 4; ++j) acc[i][j] = floatx4{0.f, 0.f, 0.f, 0.f};
    bf16x8 a0[4], b0[4];   // slice kk=0 operands
    bf16x8 a1[4], b1[4];   // slice kk=1 operands

#define STG(Tt)                                                                \
    {                                                                          \
        u16* const buf = smem + ((Tt) & 3) * 16384;                            \
        _Pragma("unroll")                                                      \
        for (int l = 0; l < 4; ++l) {                                          \
            const u16* srcA = Ab + (size_t)(l * 32 + srow) * K +               \
                              (size_t)(Tt) * 64 + scol;                        \
            __builtin_amdgcn_global_load_lds(                                  \
                AS1(srcA), AS3(buf + l * 2048 + sdst), 16, 0, 0);              \
        }                                                                      \
        _Pragma("unroll")                                                      \
        for (int l = 0; l < 4; ++l) {                                          \
            const u16* srcB = Bb + (size_t)(l * 32 + srow) * K +               \
                              (size_t)(Tt) * 64 + scol;                        \
            __builtin_amdgcn_global_load_lds(                                  \
                AS1(srcB), AS3(buf + 8192 + l * 2048 + sdst), 16, 0, 0);       \
        }                                                                      \
    }
// read one K-slice (8 x ds_read_b128) of tile Tt into (dA,dB)
#define RD_SL(dA, dB, Tt, cc)                                                  \
    {                                                                          \
        const u16* const bufA_ = smem + ((Tt) & 3) * 16384;                    \
        const u16* const bufB_ = bufA_ + 8192;                                 \
        _Pragma("unroll")                                                      \
        for (int i = 0; i < 4; ++i)                                            \
            dA[i] = *(const bf16x8*)&bufA_[(wm + i * 16 + lr) * 64 + (cc)];    \
        _Pragma("unroll")                                                      \
        for (int j = 0; j < 4; ++j)                                            \
            dB[j] = *(const bf16x8*)&bufB_[(wn + j * 16 + lr) * 64 + (cc)];    \
    }
#define MM(aR, bR)                                                             \
    _Pragma("unroll")                                                          \
    for (int i = 0; i < 4; ++i)                                                \
        _Pragma("unroll")                                                      \
        for (int j = 0; j < 4; ++j)                                            \
            acc[i][j] = __builtin_amdgcn_mfma_f32_16x16x32_bf16(               \
                aR[i], bR[j], acc[i][j], 0, 0, 0);

    // prologue: stage tiles 0,1,2; wait tiles 0,1 (tile 2 stays in flight);
    // preload (0,kk0).
    STG(0); STG(1); STG(2);
    asm volatile("s_waitcnt vmcnt(8)" ::: "memory");
    asm volatile("s_barrier" ::: "memory");
    RD_SL(a0, b0, 0, c0);

    for (int T = 0; T < NT; ++T) {
        RD_SL(a1, b1, T, c1);                       // (T,kk1) -> s1
        asm volatile("s_waitcnt lgkmcnt(8)" ::: "memory");   // s0 ready
        __builtin_amdgcn_sched_barrier(0);
        MM(a0, b0);                                 // covers s1 delivery
        if (T + 1 < NT) RD_SL(a0, b0, T + 1, c0);   // (T+1,kk0) -> s0
        if (T + 3 < NT) STG(T + 3);                 // overwrite buf (T-1)&3
        if (T + 1 < NT)
            asm volatile("s_waitcnt lgkmcnt(8)" ::: "memory");  // s1 ready
        else
            asm volatile("s_waitcnt lgkmcnt(0)" ::: "memory");
        __builtin_amdgcn_sched_barrier(0);
        MM(a1, b1);                                 // covers (T+1,kk0) delivery
        // end-sync: retire tile T+2's loads; establish invariant for T+1
        if (T + 2 < NT) {
            if (T + 3 < NT) asm volatile("s_waitcnt vmcnt(8)" ::: "memory");
            else            asm volatile("s_waitcnt vmcnt(0)" ::: "memory");
        }
        asm volatile("s_barrier" ::: "memory");
    }
#undef MM
#undef RD_SL
#undef STG

    // epilogue
#pragma unroll
    for (int i = 0; i < 4; ++i)
#pragma unroll
        for (int j = 0; j < 4; ++j) {
            const int col = n0 + wn + j * 16 + lr;
            const float bv = bias[col];
#pragma unroll
            for (int r = 0; r < 4; ++r) {
                const int row = m0 + wm + i * 16 + r0 + r;
                float x = acc[i][j][r] + bv;
                if (act) x = gelu_f(x);
                if (resid) x += resid[(size_t)row * N + col];
                if (c_f32)
                    ((float*)Cp)[(size_t)row * N + col] = x;
                else
                    ((u16*)Cp)[(size_t)row * N + col] = f2bf(x);
            }
        }
}

// ---------------------------------------------------------------------------
// Transpose the V columns of qkv [4096][3072] into vT [32*64][2048]
// ---------------------------------------------------------------------------
__global__ __launch_bounds__(256) void transp_v(const u16* __restrict__ qkv,
                                                u16* __restrict__ vT) {
    __shared__ u16 lT[64 * 64];
    const int bh = blockIdx.x, tt = blockIdx.y;
    const int b = bh >> 4, h = bh & 15;
    const int t0 = tt * 64;
    const int tid = threadIdx.x;
    const int srow = tid >> 3, scol = (tid & 7) * 8;
#pragma unroll
    for (int rr = 0; rr < 2; ++rr) {
        const int row = srow + rr * 32;  // t-local
        uint4 d4 = *(const uint4*)(qkv + (size_t)(b * 2048 + t0 + row) * 3072 +
                                   2048 + h * 64 + scol);
        const u16* e = (const u16*)&d4;
#pragma unroll
        for (int t = 0; t < 8; ++t) lT[(scol + t) * 64 + row] = e[t];
    }
    __syncthreads();
#pragma unroll
    for (int rr = 0; rr < 2; ++rr) {
        const int row = srow + rr * 32;  // d index
        uint4 d4 = *(const uint4*)&lT[row * 64 + scol];
        *(uint4*)(vT + (size_t)(bh * 64 + row) * 2048 + t0 + scol) = d4;
    }
}

// ---------------------------------------------------------------------------
// Causal flash attention v6: merged pair + max-free softmax + T2 XOR-swizzle
// on all K/V/P LDS paths + double-buffered K/V with counted vmcnt(4) +
// setprio around MFMA clusters.
// ---------------------------------------------------------------------------
__global__ __launch_bounds__(256) void attn_kernel(const u16* __restrict__ qkv,
                                                   const u16* __restrict__ vT,
                                                   u16* __restrict__ O) {
    __shared__ __align__(16) u16 lK[2][64 * 64];     // [buf][key][dh]  16 KiB
    __shared__ __align__(16) u16 lV[2][64 * 64];     // [buf][dh][key]  16 KiB
    __shared__ __align__(16) u16 lP[4][16 * 64];     // per-wave P       8 KiB
    const int tid = threadIdx.x;
    const int wave = tid >> 6, lane = tid & 63;
    const int lr = lane & 15, khi = lane >> 4, lk8 = khi * 8;
    const int p = blockIdx.x;                        // 0..15; qa=31-p first
    const int bh = blockIdx.y;
    const int b = bh >> 4, hh = bh & 15;
    const int rb = b * 2048;
    const size_t vbase = (size_t)(bh * 64) * 2048;
    const int r0 = khi * 4;
    const int qa = 31 - p, qb = p;
    const int qa0 = qa * 64, qb0 = qb * 64;
    const float C = 0.125f * 1.44269504088896f;      // scale * log2(e)

    // staging: linear LDS dest (rr*2048 + tid*8 u16), inverse-swizzled global col
    const int srow = tid >> 3;                       // 0..31
    const int scol = 8 * ((tid & 7) ^ (srow & 7));   // swizzled col within 64
    const int sdst = tid * 8;
    // read-side swizzle: col c at LDS row -> c ^ ((row&7)<<3); row&7 == lr&7
    const int swz = (lr & 7) << 3;
    const int cc0 = lk8 ^ swz;
    const int cc1 = (32 + lk8) ^ swz;

    // Q A-fragments for both tiles (direct from global; no LDS)
    bf16x8 aqA0, aqA1, aqB0, aqB1;
    {
        const size_t qoffA = (size_t)(rb + qa0 + wave * 16 + lr) * 3072 + hh * 64;
        aqA0 = *(const bf16x8*)(qkv + qoffA + lk8);
        aqA1 = *(const bf16x8*)(qkv + qoffA + 32 + lk8);
        const size_t qoffB = (size_t)(rb + qb0 + wave * 16 + lr) * 3072 + hh * 64;
        aqB0 = *(const bf16x8*)(qkv + qoffB + lk8);
        aqB1 = *(const bf16x8*)(qkv + qoffB + 32 + lk8);
    }

    floatx4 oA[4], oB[4];
    float lA_[4], lB_[4];                            // per-lane partial sums
#pragma unroll
    for (int r = 0; r < 4; ++r) {
        oA[r] = floatx4{0.f, 0.f, 0.f, 0.f};
        oB[r] = floatx4{0.f, 0.f, 0.f, 0.f};
        lA_[r] = 0.f; lB_[r] = 0.f;
    }

#define ASTAGE(Pb, kt_)                                                        \
    {                                                                          \
        const int k0_ = (kt_) * 64;                                            \
        _Pragma("unroll")                                                      \
        for (int rr = 0; rr < 2; ++rr) {                                       \
            const int row = srow + rr * 32;                                    \
            __builtin_amdgcn_global_load_lds(                                  \
                AS1(qkv + (size_t)(rb + k0_ + row) * 3072 + 1024 + hh * 64 + scol), \
                AS3(lK[Pb] + rr * 2048 + sdst), 16, 0, 0);                     \
            __builtin_amdgcn_global_load_lds(                                  \
                AS1(vT + vbase + (size_t)row * 2048 + k0_ + scol),             \
                AS3(lV[Pb] + rr * 2048 + sdst), 16, 0, 0);                     \
        }                                                                      \
    }

    // One QK->exp->PV round for one tile against the staged k-tile (buf Pb).
#define TILE_ROUND(Pb, aq0_, aq1_, oo_, ll_, q0_, diag_, k0_)                   \
    {                                                                           \
        float s[4][4];                                                          \
        __builtin_amdgcn_s_setprio(1);                                          \
        _Pragma("unroll")                                                       \
        for (int j = 0; j < 4; ++j) {                                           \
            bf16x8 bk0 = *(const bf16x8*)&lK[Pb][(j * 16 + lr) * 64 + cc0];     \
            bf16x8 bk1 = *(const bf16x8*)&lK[Pb][(j * 16 + lr) * 64 + cc1];     \
            floatx4 t = floatx4{0.f, 0.f, 0.f, 0.f};                            \
            t = __builtin_amdgcn_mfma_f32_16x16x32_bf16(aq0_, bk0, t, 0, 0, 0); \
            t = __builtin_amdgcn_mfma_f32_16x16x32_bf16(aq1_, bk1, t, 0, 0, 0); \
            _Pragma("unroll")                                                   \
            for (int r = 0; r < 4; ++r) s[j][r] = t[r];                         \
        }                                                                       \
        __builtin_amdgcn_s_setprio(0);                                          \
        if (diag_) {                                                            \
            _Pragma("unroll")                                                   \
            for (int j = 0; j < 4; ++j)                                         \
                _Pragma("unroll")                                               \
                for (int r = 0; r < 4; ++r)                                     \
                    if ((k0_) + j * 16 + lr > (q0_) + wave * 16 + r0 + r)       \
                        s[j][r] = -1e30f;                                       \
        }                                                                       \
        _Pragma("unroll")                                                       \
        for (int j = 0; j < 4; ++j)                                             \
            _Pragma("unroll")                                                   \
            for (int r = 0; r < 4; ++r) {                                       \
                float pv = exp2_fast(s[j][r] * C);                              \
                ll_[r] += pv;                                                   \
                lP[wave][(r0 + r) * 64 +                                        \
                         ((j * 16 + lr) ^ (((r0 + r) & 7) << 3))] =             \
                    f2bf_trunc(pv);                                             \
            }                                                                   \
        bf16x8 ap0 = *(const bf16x8*)&lP[wave][lr * 64 + cc0];                  \
        bf16x8 ap1 = *(const bf16x8*)&lP[wave][lr * 64 + cc1];                  \
        __builtin_amdgcn_s_setprio(1);                                          \
        _Pragma("unroll")                                                       \
        for (int jd = 0; jd < 4; ++jd) {                                        \
            bf16x8 bv0 = *(const bf16x8*)&lV[Pb][(jd * 16 + lr) * 64 + cc0];    \
            bf16x8 bv1 = *(const bf16x8*)&lV[Pb][(jd * 16 + lr) * 64 + cc1];    \
            oo_[jd] = __builtin_amdgcn_mfma_f32_16x16x32_bf16(ap0, bv0, oo_[jd], 0, 0, 0); \
            oo_[jd] = __builtin_amdgcn_mfma_f32_16x16x32_bf16(ap1, bv1, oo_[jd], 0, 0, 0); \
        }                                                                       \
        __builtin_amdgcn_s_setprio(0);                                          \
    }

    ASTAGE(0, 0);
    for (int kt = 0; kt <= qa; ++kt) {
        const int P = kt & 1;
        const int k0 = kt * 64;
        if (kt < qa) {
            ASTAGE(P ^ 1, kt + 1);
            asm volatile("s_waitcnt vmcnt(4)" ::: "memory");
        } else {
            asm volatile("s_waitcnt vmcnt(0)" ::: "memory");
        }
        asm volatile("s_barrier" ::: "memory");

        TILE_ROUND(P, aqA0, aqA1, oA, lA_, qa0, kt == qa, k0);
        if (kt <= qb)
            TILE_ROUND(P, aqB0, aqB1, oB, lB_, qb0, kt == qb, k0);

        asm volatile("s_barrier" ::: "memory");  // retire buf-P reads before restage
    }
#undef TILE_ROUND
#undef ASTAGE

    // one-time denominator reduce over the 16 lanes sharing khi (lr bits)
#pragma unroll
    for (int off = 1; off < 16; off <<= 1)
#pragma unroll
        for (int r = 0; r < 4; ++r) {
            lA_[r] += __shfl_xor(lA_[r], off, 64);
            lB_[r] += __shfl_xor(lB_[r], off, 64);
        }

    // normalize + store ctx for both tiles (lane's rows are khi*4+r)
#pragma unroll
    for (int r = 0; r < 4; ++r) {
        const float invA = 1.0f / lA_[r];
        const float invB = 1.0f / lB_[r];
#pragma unroll
        for (int jd = 0; jd < 4; ++jd) {
            const size_t offA = (size_t)(rb + qa0 + wave * 16 + r0 + r) * 1024 +
                                hh * 64 + jd * 16 + lr;
            O[offA] = f2bf(oA[jd][r] * invA);
            const size_t offB = (size_t)(rb + qb0 + wave * 16 + r0 + r) * 1024 +
                                hh * 64 + jd * 16 + lr;
            O[offB] = f2bf(oB[jd][r] * invB);
        }
    }
}

// ---------------------------------------------------------------------------
extern "C" void kernel_launch(void* const* d_in, const int* in_sizes, int n_in,
                              void* d_out, int out_size, void* d_ws, size_t ws_size,
                              hipStream_t stream) {
    const float* x     = (const float*)d_in[0];
    // d_in[1] = causal mask (deterministic, unused)
    const float* wq_w  = (const float*)d_in[2];
    const float* wq_b  = (const float*)d_in[3];
    const float* wk_w  = (const float*)d_in[4];
    const float* wk_b  = (const float*)d_in[5];
    const float* wv_w  = (const float*)d_in[6];
    const float* wv_b  = (const float*)d_in[7];
    const float* wo_w  = (const float*)d_in[8];
    const float* wo_b  = (const float*)d_in[9];
    const float* fc1_w = (const float*)d_in[10];
    const float* fc1_b = (const float*)d_in[11];
    const float* fc2_w = (const float*)d_in[12];
    const float* fc2_b = (const float*)d_in[13];
    const float* ln1_g = (const float*)d_in[14];
    const float* ln1_b = (const float*)d_in[15];
    const float* ln2_g = (const float*)d_in[16];
    const float* ln2_b = (const float*)d_in[17];
    float* out = (float*)d_out;

    char* ws = (char*)d_ws;
    const size_t M1 = 1048576;
    const size_t MB = 1048576;
    u16* Wc    = (u16*)ws;
    u16* wqc   = Wc;                       // [3072][1024] fused qkv rows
    u16* woc   = Wc + 3 * M1;
    u16* f1c   = Wc + 4 * M1;
    u16* f2c   = Wc + 8 * M1;
    u16* h     = (u16*)(ws + 24 * MB);
    u16* ctx   = h;
    u16* qkv   = (u16*)(ws + 32 * MB);
    u16* vT    = (u16*)(ws + 56 * MB);
    u16* ffh   = (u16*)(ws + 32 * MB);
    float* x1  = (float*)(ws + 64 * MB);
    float* qkvb = x1;                      // 3072 fp32, dead before x1 written
    u16* h2    = h;

    const dim3 blk(256);

    static bool s_attr_done = false;
    if (!s_attr_done) {
        hipFuncSetAttribute(reinterpret_cast<const void*>(gemm128p_kernel),
                            hipFuncAttributeMaxDynamicSharedMemorySize, 131072);
        s_attr_done = true;
    }

    // 0. weights fp32 -> bf16 (+ fused qkv bias)
    conv_w_kernel<<<12288, 256, 0, stream>>>(wq_w, wk_w, wv_w, wo_w, fc1_w, fc2_w,
                                             wq_b, wk_b, wv_b, qkvb, Wc);
    // 1. h = LN1(x)
    ln_kernel<<<4096, 64, 0, stream>>>(x, ln1_g, ln1_b, h);
    // 2. qkv = h @ [Wq;Wk;Wv]^T + b   (fused, N=3072; bf16 out)
    gemm128p_kernel<<<dim3(32, 24), blk, 131072, stream>>>(
        h, wqc, qkvb, nullptr, qkv, 4096, 3072, 1024, 0, 0);
    // 3. vT = per-head transpose of V
    transp_v<<<dim3(32, 32), blk, 0, stream>>>(qkv, vT);
    // 4. ctx = causal_attn(q,k,vT)
    attn_kernel<<<dim3(16, 32), blk, 0, stream>>>(qkv, vT, ctx);
    // 5. x1 = x + ctx @ Wo^T + bo    (fp32 out + resid)
    gemm128p_kernel<<<dim3(32, 8), blk, 131072, stream>>>(
        ctx, woc, wo_b, x, x1, 4096, 1024, 1024, 0, 1);
    // 6. h2 = LN2(x1)
    ln_kernel<<<4096, 64, 0, stream>>>(x1, ln2_g, ln2_b, h2);
    // 7. ffh = gelu(h2 @ fc1^T + b1) (bf16 out)
    gemm128p_kernel<<<dim3(32, 32), blk, 131072, stream>>>(
        h2, f1c, fc1_b, nullptr, ffh, 4096, 4096, 1024, 1, 0);
    // 8. out = x1 + ffh @ fc2^T + b2 (fp32 out + resid)
    gemm128p_kernel<<<dim3(32, 8), blk, 131072, stream>>>(
        ffh, f2c, fc2_b, x1, out, 4096, 1024, 4096, 0, 1);
}

// Round 8
// 352.447 us; speedup vs baseline: 1.2333x; 1.2333x over previous
//
#include <hip/hip_runtime.h>
#include <stdint.h>

typedef unsigned short u16;
typedef __bf16 bf16x8 __attribute__((ext_vector_type(8)));
typedef float floatx4 __attribute__((ext_vector_type(4)));

#define AS1(p) ((__attribute__((address_space(1))) void*)(void*)(p))
#define AS3(p) ((__attribute__((address_space(3))) void*)(p))

__device__ __forceinline__ u16 f2bf(float f) {
    unsigned u;
    __builtin_memcpy(&u, &f, 4);
    u += 0x7FFF + ((u >> 16) & 1);   // RNE
    return (u16)(u >> 16);
}
__device__ __forceinline__ u16 f2bf_trunc(float f) {
    unsigned u;
    __builtin_memcpy(&u, &f, 4);
    return (u16)(u >> 16);
}
__device__ __forceinline__ float exp2_fast(float x) {
    return __builtin_amdgcn_exp2f(x);    // v_exp_f32
}
__device__ __forceinline__ float gelu_f(float x) {
    return 0.5f * x * (1.0f + erff(x * 0.70710678118654752f));
}

// ---------------------------------------------------------------------------
// Convert the 6 weight matrices fp32 -> bf16 into ws (layout: wq wk wv wo f1 f2)
// ---------------------------------------------------------------------------
__global__ __launch_bounds__(256) void conv_w_kernel(
    const float* __restrict__ wq, const float* __restrict__ wk,
    const float* __restrict__ wv, const float* __restrict__ wo,
    const float* __restrict__ f1, const float* __restrict__ f2,
    const float* __restrict__ bq, const float* __restrict__ bk,
    const float* __restrict__ bv, float* __restrict__ qkvb,
    u16* __restrict__ W) {
    const size_t i4 = ((size_t)blockIdx.x * 256 + threadIdx.x) * 4;
    const size_t M1 = 1048576;
    const float* src;
    size_t off;
    if (i4 < M1)            { src = wq; off = i4; }
    else if (i4 < 2 * M1)   { src = wk; off = i4 - M1; }
    else if (i4 < 3 * M1)   { src = wv; off = i4 - 2 * M1; }
    else if (i4 < 4 * M1)   { src = wo; off = i4 - 3 * M1; }
    else if (i4 < 8 * M1)   { src = f1; off = i4 - 4 * M1; }
    else                    { src = f2; off = i4 - 8 * M1; }
    float4 d = *(const float4*)(src + off);
    ushort4 o;
    o.x = f2bf(d.x); o.y = f2bf(d.y); o.z = f2bf(d.z); o.w = f2bf(d.w);
    *(ushort4*)(W + i4) = o;
    if (blockIdx.x == 0) {
        for (int i = threadIdx.x; i < 1024; i += 256) {
            qkvb[i] = bq[i];
            qkvb[1024 + i] = bk[i];
            qkvb[2048 + i] = bv[i];
        }
    }
}

// ---------------------------------------------------------------------------
// LayerNorm: one wave per token row (D=1024 -> 16 elems/lane). fp32 in, bf16 out.
// ---------------------------------------------------------------------------
__global__ __launch_bounds__(64) void ln_kernel(const float* __restrict__ X,
                                                const float* __restrict__ G,
                                                const float* __restrict__ Bt,
                                                u16* __restrict__ Y) {
    const int row = blockIdx.x;
    const int lane = threadIdx.x;
    const float* xr = X + (size_t)row * 1024;
    float v[16];
    float s = 0.f;
#pragma unroll
    for (int i = 0; i < 16; ++i) { v[i] = xr[lane + i * 64]; s += v[i]; }
#pragma unroll
    for (int off = 1; off < 64; off <<= 1) s += __shfl_xor(s, off, 64);
    const float mu = s * (1.0f / 1024.0f);
    float ss = 0.f;
#pragma unroll
    for (int i = 0; i < 16; ++i) { float d = v[i] - mu; ss += d * d; }
#pragma unroll
    for (int off = 1; off < 64; off <<= 1) ss += __shfl_xor(ss, off, 64);
    const float rstd = rsqrtf(ss * (1.0f / 1024.0f) + 1e-5f);
    u16* yr = Y + (size_t)row * 1024;
#pragma unroll
    for (int i = 0; i < 16; ++i) {
        int c = lane + i * 64;
        yr[c] = f2bf((v[i] - mu) * rstd * G[c] + Bt[c]);
    }
}

// ---------------------------------------------------------------------------
// gemm128sq: 128x128 tile, 4 waves (2Mx2N, 64x64 each), BK=64,
// 4-buffer LDS pipeline staged 3 tiles ahead (counted vmcnt 16/8/0 tail),
// T2 XOR-swizzle (rule #21), setprio around the 32-MFMA cluster.
// fp32 out = A@Bt^T + bias + resid. Grid (M/128, N/128). 128 KiB dyn LDS.
// ---------------------------------------------------------------------------
__global__ __launch_bounds__(256, 1) void gemm128sq_kernel(
    const u16* __restrict__ A, const u16* __restrict__ Bt,
    const float* __restrict__ bias, const float* __restrict__ resid,
    float* __restrict__ C, int M, int N, int K) {
    extern __shared__ __align__(16) u16 smem[];   // 4 bufs x (A 8192 + B 8192) u16
    const int tid = threadIdx.x;
    const int wave = tid >> 6, lane = tid & 63;
    const int wm = (wave >> 1) * 64;
    const int wn = (wave & 1) * 64;
    const int lr = lane & 15, lk8 = (lane >> 4) * 8;
    const int r0 = (lane >> 4) * 4;
    const int m0 = blockIdx.x * 128, n0 = blockIdx.y * 128;
    const int NT = K >> 6;                        // 16 or 64
    const u16* const Ab = A + (size_t)m0 * K;
    const u16* const Bb = Bt + (size_t)n0 * K;

    const int srow = tid >> 3;                    // 0..31
    const int scol = 8 * ((tid & 7) ^ (srow & 7));
    const int sdst = tid * 8;                     // u16 offset within 2048-u16 chunk
    const int swz = (lr & 7) << 3;
    const int c0 = lk8 ^ swz;
    const int c1 = (32 + lk8) ^ swz;

    floatx4 acc[4][4];
#pragma unroll
    for (int i = 0; i < 4; ++i)
#pragma unroll
        for (int j = 0; j < 4; ++j) acc[i][j] = floatx4{0.f, 0.f, 0.f, 0.f};
    bf16x8 aF[4][2], bF[4][2];

#define STG(Tt)                                                                \
    {                                                                          \
        u16* const buf = smem + ((Tt) & 3) * 16384;                            \
        _Pragma("unroll")                                                      \
        for (int l = 0; l < 4; ++l) {                                          \
            const u16* srcA = Ab + (size_t)(l * 32 + srow) * K +               \
                              (size_t)(Tt) * 64 + scol;                        \
            __builtin_amdgcn_global_load_lds(                                  \
                AS1(srcA), AS3(buf + l * 2048 + sdst), 16, 0, 0);              \
        }                                                                      \
        _Pragma("unroll")                                                      \
        for (int l = 0; l < 4; ++l) {                                          \
            const u16* srcB = Bb + (size_t)(l * 32 + srow) * K +               \
                              (size_t)(Tt) * 64 + scol;                        \
            __builtin_amdgcn_global_load_lds(                                  \
                AS1(srcB), AS3(buf + 8192 + l * 2048 + sdst), 16, 0, 0);       \
        }                                                                      \
    }

    STG(0); STG(1); STG(2);
    for (int T = 0; T < NT; ++T) {
        const int rem = NT - 1 - T;
        if (rem >= 2)      asm volatile("s_waitcnt vmcnt(16)" ::: "memory");
        else if (rem == 1) asm volatile("s_waitcnt vmcnt(8)" ::: "memory");
        else               asm volatile("s_waitcnt vmcnt(0)" ::: "memory");
        asm volatile("s_barrier" ::: "memory");
        if (T + 3 < NT) STG(T + 3);
        const u16* const bufA = smem + (T & 3) * 16384;
        const u16* const bufB = bufA + 8192;
#pragma unroll
        for (int i = 0; i < 4; ++i) {
            aF[i][0] = *(const bf16x8*)&bufA[(wm + i * 16 + lr) * 64 + c0];
            aF[i][1] = *(const bf16x8*)&bufA[(wm + i * 16 + lr) * 64 + c1];
        }
#pragma unroll
        for (int j = 0; j < 4; ++j) {
            bF[j][0] = *(const bf16x8*)&bufB[(wn + j * 16 + lr) * 64 + c0];
            bF[j][1] = *(const bf16x8*)&bufB[(wn + j * 16 + lr) * 64 + c1];
        }
        asm volatile("s_waitcnt lgkmcnt(0)" ::: "memory");
        __builtin_amdgcn_sched_barrier(0);
        __builtin_amdgcn_s_setprio(1);
#pragma unroll
        for (int i = 0; i < 4; ++i)
#pragma unroll
            for (int j = 0; j < 4; ++j)
#pragma unroll
                for (int kk = 0; kk < 2; ++kk)
                    acc[i][j] = __builtin_amdgcn_mfma_f32_16x16x32_bf16(
                        aF[i][kk], bF[j][kk], acc[i][j], 0, 0, 0);
        __builtin_amdgcn_s_setprio(0);
    }
#undef STG

    // epilogue: fp32 out = acc + bias + resid
#pragma unroll
    for (int i = 0; i < 4; ++i)
#pragma unroll
        for (int j = 0; j < 4; ++j) {
            const int col = n0 + wn + j * 16 + lr;
            const float bv = bias[col];
#pragma unroll
            for (int r = 0; r < 4; ++r) {
                const int row = m0 + wm + i * 16 + r0 + r;
                C[(size_t)row * N + col] =
                    acc[i][j][r] + bv + resid[(size_t)row * N + col];
            }
        }
}

// ---------------------------------------------------------------------------
// gemm256 v4: 256x256 tile, BK=64, 8 waves (2Mx4N), faithful m201 anatomy.
// Per tile-window W(T) (parity P=T&1), 4 phases, EACH phase:
//   {ds_reads for one C-quadrant | stage exactly 1 half-tile} -> BAR ->
//   lgkm0 -> setprio(1) 16xMFMA setprio(0) -> BAR
// MFMA clusters are barrier-isolated; reads/stage never share their region.
// Stage rotation (1 HT per phase):
//   ph1: A(T+1)h0 -> A-buf(P^1)   [free since W(T-1).ph3 retire]
//   ph2: A(T+1)h1 -> A-buf(P^1)
//   ph3: B(T+2)h0 -> B-buf(P)     [B(T) reads retired at ph2]
//   ph4: B(T+2)h1 -> B-buf(P)
// vmcnt(4) ONCE per window (at ph4, after MFMA, before final BAR):
//   in-flight = B(T+1)(4) A(T+1)(4) B(T+2)(4) -> keep newest 4 = B(T+2),
//   retire A(T+1)+B(T+1) exactly before W(T+1) reads them. Tail: vmcnt(0).
// Prologue: stage A0,B0 (8) + B1 (4); vmcnt(4) keeps B1; BAR.
// Register diet kept: single aF[4][2] (round-4 spill-cliff lesson).
// ---------------------------------------------------------------------------
__global__ __launch_bounds__(512, 2) void gemm256_kernel(
    const u16* __restrict__ A, const u16* __restrict__ Bt,
    const float* __restrict__ bias, u16* __restrict__ C,
    int M, int N, int K, int act) {
    extern __shared__ __align__(16) u16 smem[];
    u16* const lA = smem;          // [2][256*64] = 64 KiB
    u16* const lB = smem + 32768;  // [2][256*64] = 64 KiB
    const int tid = threadIdx.x;
    const int wave = tid >> 6, lane = tid & 63;
    const int wm = (wave >> 2) * 128;        // wave M-origin (0/128)
    const int wn = (wave & 3) * 64;          // wave N-origin (0/64/128/192)
    const int lr = lane & 15, lk8 = (lane >> 4) * 8;
    const int r0 = (lane >> 4) * 4;

    const int gM = M >> 8;
    int bid = blockIdx.x;
    { const int nwg = gridDim.x;
      const int q = nwg >> 3, r = nwg & 7, xcd = bid & 7, lid = bid >> 3;
      bid = (xcd < r ? xcd * (q + 1) : r * (q + 1) + (xcd - r) * q) + lid; }
    const int m0 = (bid % gM) << 8;
    const int n0 = (bid / gM) << 8;

    const int NT = K >> 6;                   // 16 here (even, >=4)
    const u16* const Ab = A + (size_t)m0 * K;
    const u16* const Bb = Bt + (size_t)n0 * K;

    const int srow = tid >> 3;                         // 0..63
    const int scol = 8 * ((tid & 7) ^ (srow & 7));     // element col, inv-swizzled
    const int sdst = tid * 8;                          // u16 offset (lane*16 B)
    const int swz = (lr & 7) << 3;
    const int c0 = lk8 ^ swz;                          // kk=0 frag col
    const int c1 = (32 + lk8) ^ swz;                   // kk=1 frag col

    floatx4 acc[8][4];
#pragma unroll
    for (int i = 0; i < 8; ++i)
#pragma unroll
        for (int j = 0; j < 4; ++j) acc[i][j] = floatx4{0.f, 0.f, 0.f, 0.f};
    bf16x8 aF[4][2];      // current mq half only (overwritten at ph3)
    bf16x8 bF[4][2];      // [nf][kk]

#define STAGE_HT(ldsbuf, gbase, h, Tt)                                         \
    {                                                                          \
        _Pragma("unroll")                                                      \
        for (int l = 0; l < 2; ++l) {                                          \
            const u16* src = (gbase) + (size_t)((h) * 128 + l * 64 + srow) * K \
                             + (size_t)(Tt) * 64 + scol;                       \
            __builtin_amdgcn_global_load_lds(                                  \
                AS1(src), AS3((ldsbuf) + (h) * 8192 + l * 4096 + sdst), 16, 0, 0); \
        }                                                                      \
    }
#define PH_BAR() asm volatile("s_barrier" ::: "memory")
#define LGKM0()                                                                \
    do { asm volatile("s_waitcnt lgkmcnt(0)" ::: "memory");                    \
         __builtin_amdgcn_sched_barrier(0); } while (0)
#define RD_A(lAp, mq)                                                          \
    _Pragma("unroll")                                                          \
    for (int i = 0; i < 4; ++i) {                                              \
        aF[i][0] = *(const bf16x8*)&(lAp)[(wm + (mq) * 64 + i * 16 + lr) * 64 + c0]; \
        aF[i][1] = *(const bf16x8*)&(lAp)[(wm + (mq) * 64 + i * 16 + lr) * 64 + c1]; \
    }
#define RD_B2(lBp, nf0)                                                        \
    _Pragma("unroll")                                                          \
    for (int j = 0; j < 2; ++j) {                                              \
        bF[(nf0) + j][0] = *(const bf16x8*)&(lBp)[(wn + ((nf0) + j) * 16 + lr) * 64 + c0]; \
        bF[(nf0) + j][1] = *(const bf16x8*)&(lBp)[(wn + ((nf0) + j) * 16 + lr) * 64 + c1]; \
    }
#define MFMA_Q(mq, nq)                                                         \
    __builtin_amdgcn_s_setprio(1);                                             \
    _Pragma("unroll")                                                          \
    for (int i = 0; i < 4; ++i)                                                \
        _Pragma("unroll")                                                      \
        for (int j = 0; j < 2; ++j)                                            \
            _Pragma("unroll")                                                  \
            for (int kk = 0; kk < 2; ++kk)                                     \
                acc[(mq) * 4 + i][(nq) * 2 + j] =                              \
                    __builtin_amdgcn_mfma_f32_16x16x32_bf16(                   \
                        aF[i][kk], bF[(nq) * 2 + j][kk],                       \
                        acc[(mq) * 4 + i][(nq) * 2 + j], 0, 0, 0);             \
    __builtin_amdgcn_s_setprio(0);

#define WINDOW(P, T)                                                           \
    {                                                                          \
        u16* const lAp = lA + (P) * 16384;                                     \
        u16* const lBp = lB + (P) * 16384;                                     \
        u16* const lAn = lA + ((P) ^ 1) * 16384;                               \
        /* ph1: reads for Q(0,0); stage A(T+1)h0 */                            \
        RD_A(lAp, 0);                                                          \
        RD_B2(lBp, 0);                                                         \
        if ((T) + 1 < NT) STAGE_HT(lAn, Ab, 0, (T) + 1);                       \
        PH_BAR(); LGKM0();                                                     \
        MFMA_Q(0, 0);                                                          \
        PH_BAR();                                                              \
        /* ph2: reads for Q(0,1); stage A(T+1)h1 */                            \
        RD_B2(lBp, 2);                                                         \
        if ((T) + 1 < NT) STAGE_HT(lAn, Ab, 1, (T) + 1);                       \
        PH_BAR(); LGKM0();                                                     \
        MFMA_Q(0, 1);                                                          \
        PH_BAR();                                                              \
        /* ph3: reads for Q(1,0); stage B(T+2)h0 (B(T) reads retired @ph2) */  \
        RD_A(lAp, 1);                                                          \
        if ((T) + 2 < NT) STAGE_HT(lBp, Bb, 0, (T) + 2);                       \
        PH_BAR(); LGKM0();                                                     \
        MFMA_Q(1, 0);                                                          \
        PH_BAR();                                                              \
        /* ph4: stage B(T+2)h1; MFMA Q(1,1); counted vmcnt; BAR */             \
        if ((T) + 2 < NT) STAGE_HT(lBp, Bb, 1, (T) + 2);                       \
        MFMA_Q(1, 1);                                                          \
        if ((T) + 2 < NT) asm volatile("s_waitcnt vmcnt(4)" ::: "memory");     \
        else              asm volatile("s_waitcnt vmcnt(0)" ::: "memory");     \
        PH_BAR();                                                              \
    }

    // prologue: A0,B0 (8 loads) + B1 (4 loads); keep B1 in flight
    STAGE_HT(lA, Ab, 0, 0);
    STAGE_HT(lA, Ab, 1, 0);
    STAGE_HT(lB, Bb, 0, 0);
    STAGE_HT(lB, Bb, 1, 0);
    if (NT > 1) {
        STAGE_HT(lB + 16384, Bb, 0, 1);
        STAGE_HT(lB + 16384, Bb, 1, 1);
    }
    asm volatile("s_waitcnt vmcnt(4)" ::: "memory");
    PH_BAR();

    for (int T = 0; T < NT; T += 2) {
        WINDOW(0, T);
        WINDOW(1, T + 1);
    }
#undef WINDOW
#undef MFMA_Q
#undef RD_B2
#undef RD_A
#undef LGKM0
#undef PH_BAR
#undef STAGE_HT

    // epilogue: bias (+gelu) -> bf16
#pragma unroll
    for (int mq = 0; mq < 2; ++mq)
#pragma unroll
        for (int i = 0; i < 4; ++i)
#pragma unroll
            for (int nf = 0; nf < 4; ++nf) {
                const int col = n0 + wn + nf * 16 + lr;
                const float bv = bias[col];
                floatx4 v = acc[mq * 4 + i][nf];
#pragma unroll
                for (int r = 0; r < 4; ++r) {
                    const int row = m0 + wm + mq * 64 + i * 16 + r0 + r;
                    float x = v[r] + bv;
                    if (act) x = gelu_f(x);
                    C[(size_t)row * N + col] = f2bf(x);
                }
            }
}

// ---------------------------------------------------------------------------
// Transpose the V columns of qkv [4096][3072] into vT [32*64][2048]
// ---------------------------------------------------------------------------
__global__ __launch_bounds__(256) void transp_v(const u16* __restrict__ qkv,
                                                u16* __restrict__ vT) {
    __shared__ u16 lT[64 * 64];
    const int bh = blockIdx.x, tt = blockIdx.y;
    const int b = bh >> 4, h = bh & 15;
    const int t0 = tt * 64;
    const int tid = threadIdx.x;
    const int srow = tid >> 3, scol = (tid & 7) * 8;
#pragma unroll
    for (int rr = 0; rr < 2; ++rr) {
        const int row = srow + rr * 32;  // t-local
        uint4 d4 = *(const uint4*)(qkv + (size_t)(b * 2048 + t0 + row) * 3072 +
                                   2048 + h * 64 + scol);
        const u16* e = (const u16*)&d4;
#pragma unroll
        for (int t = 0; t < 8; ++t) lT[(scol + t) * 64 + row] = e[t];
    }
    __syncthreads();
#pragma unroll
    for (int rr = 0; rr < 2; ++rr) {
        const int row = srow + rr * 32;  // d index
        uint4 d4 = *(const uint4*)&lT[row * 64 + scol];
        *(uint4*)(vT + (size_t)(bh * 64 + row) * 2048 + t0 + scol) = d4;
    }
}

// ---------------------------------------------------------------------------
// Causal flash attention v6: merged pair + max-free softmax + T2 XOR-swizzle
// on all K/V/P LDS paths + double-buffered K/V with counted vmcnt(4) +
// setprio around MFMA clusters.
// ---------------------------------------------------------------------------
__global__ __launch_bounds__(256) void attn_kernel(const u16* __restrict__ qkv,
                                                   const u16* __restrict__ vT,
                                                   u16* __restrict__ O) {
    __shared__ __align__(16) u16 lK[2][64 * 64];     // [buf][key][dh]  16 KiB
    __shared__ __align__(16) u16 lV[2][64 * 64];     // [buf][dh][key]  16 KiB
    __shared__ __align__(16) u16 lP[4][16 * 64];     // per-wave P       8 KiB
    const int tid = threadIdx.x;
    const int wave = tid >> 6, lane = tid & 63;
    const int lr = lane & 15, khi = lane >> 4, lk8 = khi * 8;
    const int p = blockIdx.x;                        // 0..15; qa=31-p first
    const int bh = blockIdx.y;
    const int b = bh >> 4, hh = bh & 15;
    const int rb = b * 2048;
    const size_t vbase = (size_t)(bh * 64) * 2048;
    const int srow = tid >> 3, scol = 8 * ((tid & 7) ^ ((tid >> 3) & 7));
    const int sdst = tid * 8;
    const int r0 = khi * 4;
    const int qa = 31 - p, qb = p;
    const int qa0 = qa * 64, qb0 = qb * 64;
    const float C = 0.125f * 1.44269504088896f;      // scale * log2(e)

    const int swz = (lr & 7) << 3;
    const int cc0 = lk8 ^ swz;
    const int cc1 = (32 + lk8) ^ swz;

    // Q A-fragments for both tiles (direct from global; no LDS)
    bf16x8 aqA0, aqA1, aqB0, aqB1;
    {
        const size_t qoffA = (size_t)(rb + qa0 + wave * 16 + lr) * 3072 + hh * 64;
        aqA0 = *(const bf16x8*)(qkv + qoffA + lk8);
        aqA1 = *(const bf16x8*)(qkv + qoffA + 32 + lk8);
        const size_t qoffB = (size_t)(rb + qb0 + wave * 16 + lr) * 3072 + hh * 64;
        aqB0 = *(const bf16x8*)(qkv + qoffB + lk8);
        aqB1 = *(const bf16x8*)(qkv + qoffB + 32 + lk8);
    }

    floatx4 oA[4], oB[4];
    float lA_[4], lB_[4];                            // per-lane partial sums
#pragma unroll
    for (int r = 0; r < 4; ++r) {
        oA[r] = floatx4{0.f, 0.f, 0.f, 0.f};
        oB[r] = floatx4{0.f, 0.f, 0.f, 0.f};
        lA_[r] = 0.f; lB_[r] = 0.f;
    }

#define ASTAGE(Pb, kt_)                                                        \
    {                                                                          \
        const int k0_ = (kt_) * 64;                                            \
        _Pragma("unroll")                                                      \
        for (int rr = 0; rr < 2; ++rr) {                                       \
            const int row = srow + rr * 32;                                    \
            __builtin_amdgcn_global_load_lds(                                  \
                AS1(qkv + (size_t)(rb + k0_ + row) * 3072 + 1024 + hh * 64 + scol), \
                AS3(lK[Pb] + rr * 2048 + sdst), 16, 0, 0);                     \
            __builtin_amdgcn_global_load_lds(                                  \
                AS1(vT + vbase + (size_t)row * 2048 + k0_ + scol),             \
                AS3(lV[Pb] + rr * 2048 + sdst), 16, 0, 0);                     \
        }                                                                      \
    }

    // One QK->exp->PV round for one tile against the staged k-tile (buf Pb).
#define TILE_ROUND(Pb, aq0_, aq1_, oo_, ll_, q0_, diag_, k0_)                   \
    {                                                                           \
        float s[4][4];                                                          \
        __builtin_amdgcn_s_setprio(1);                                          \
        _Pragma("unroll")                                                       \
        for (int j = 0; j < 4; ++j) {                                           \
            bf16x8 bk0 = *(const bf16x8*)&lK[Pb][(j * 16 + lr) * 64 + cc0];     \
            bf16x8 bk1 = *(const bf16x8*)&lK[Pb][(j * 16 + lr) * 64 + cc1];     \
            floatx4 t = floatx4{0.f, 0.f, 0.f, 0.f};                            \
            t = __builtin_amdgcn_mfma_f32_16x16x32_bf16(aq0_, bk0, t, 0, 0, 0); \
            t = __builtin_amdgcn_mfma_f32_16x16x32_bf16(aq1_, bk1, t, 0, 0, 0); \
            _Pragma("unroll")                                                   \
            for (int r = 0; r < 4; ++r) s[j][r] = t[r];                         \
        }                                                                       \
        __builtin_amdgcn_s_setprio(0);                                          \
        if (diag_) {                                                            \
            _Pragma("unroll")                                                   \
            for (int j = 0; j < 4; ++j)                                         \
                _Pragma("unroll")                                               \
                for (int r = 0; r < 4; ++r)                                     \
                    if ((k0_) + j * 16 + lr > (q0_) + wave * 16 + r0 + r)       \
                        s[j][r] = -1e30f;                                       \
        }                                                                       \
        _Pragma("unroll")                                                       \
        for (int j = 0; j < 4; ++j)                                             \
            _Pragma("unroll")                                                   \
            for (int r = 0; r < 4; ++r) {                                       \
                float pv = exp2_fast(s[j][r] * C);                              \
                ll_[r] += pv;                                                   \
                lP[wave][(r0 + r) * 64 +                                        \
                         ((j * 16 + lr) ^ (((r0 + r) & 7) << 3))] =             \
                    f2bf_trunc(pv);                                             \
            }                                                                   \
        bf16x8 ap0 = *(const bf16x8*)&lP[wave][lr * 64 + cc0];                  \
        bf16x8 ap1 = *(const bf16x8*)&lP[wave][lr * 64 + cc1];                  \
        __builtin_amdgcn_s_setprio(1);                                          \
        _Pragma("unroll")                                                       \
        for (int jd = 0; jd < 4; ++jd) {                                        \
            bf16x8 bv0 = *(const bf16x8*)&lV[Pb][(jd * 16 + lr) * 64 + cc0];    \
            bf16x8 bv1 = *(const bf16x8*)&lV[Pb][(jd * 16 + lr) * 64 + cc1];    \
            oo_[jd] = __builtin_amdgcn_mfma_f32_16x16x32_bf16(ap0, bv0, oo_[jd], 0, 0, 0); \
            oo_[jd] = __builtin_amdgcn_mfma_f32_16x16x32_bf16(ap1, bv1, oo_[jd], 0, 0, 0); \
        }                                                                       \
        __builtin_amdgcn_s_setprio(0);                                          \
    }

    ASTAGE(0, 0);
    for (int kt = 0; kt <= qa; ++kt) {
        const int P = kt & 1;
        const int k0 = kt * 64;
        if (kt < qa) {
            ASTAGE(P ^ 1, kt + 1);
            asm volatile("s_waitcnt vmcnt(4)" ::: "memory");
        } else {
            asm volatile("s_waitcnt vmcnt(0)" ::: "memory");
        }
        asm volatile("s_barrier" ::: "memory");

        TILE_ROUND(P, aqA0, aqA1, oA, lA_, qa0, kt == qa, k0);
        if (kt <= qb)
            TILE_ROUND(P, aqB0, aqB1, oB, lB_, qb0, kt == qb, k0);

        asm volatile("s_barrier" ::: "memory");  // retire buf-P reads before restage
    }
#undef TILE_ROUND
#undef ASTAGE

    // one-time denominator reduce over the 16 lanes sharing khi (lr bits)
#pragma unroll
    for (int off = 1; off < 16; off <<= 1)
#pragma unroll
        for (int r = 0; r < 4; ++r) {
            lA_[r] += __shfl_xor(lA_[r], off, 64);
            lB_[r] += __shfl_xor(lB_[r], off, 64);
        }

    // normalize + store ctx for both tiles (lane's rows are khi*4+r)
#pragma unroll
    for (int r = 0; r < 4; ++r) {
        const float invA = 1.0f / lA_[r];
        const float invB = 1.0f / lB_[r];
#pragma unroll
        for (int jd = 0; jd < 4; ++jd) {
            const size_t offA = (size_t)(rb + qa0 + wave * 16 + r0 + r) * 1024 +
                                hh * 64 + jd * 16 + lr;
            O[offA] = f2bf(oA[jd][r] * invA);
            const size_t offB = (size_t)(rb + qb0 + wave * 16 + r0 + r) * 1024 +
                                hh * 64 + jd * 16 + lr;
            O[offB] = f2bf(oB[jd][r] * invB);
        }
    }
}

// ---------------------------------------------------------------------------
extern "C" void kernel_launch(void* const* d_in, const int* in_sizes, int n_in,
                              void* d_out, int out_size, void* d_ws, size_t ws_size,
                              hipStream_t stream) {
    const float* x     = (const float*)d_in[0];
    // d_in[1] = causal mask (deterministic, unused)
    const float* wq_w  = (const float*)d_in[2];
    const float* wq_b  = (const float*)d_in[3];
    const float* wk_w  = (const float*)d_in[4];
    const float* wk_b  = (const float*)d_in[5];
    const float* wv_w  = (const float*)d_in[6];
    const float* wv_b  = (const float*)d_in[7];
    const float* wo_w  = (const float*)d_in[8];
    const float* wo_b  = (const float*)d_in[9];
    const float* fc1_w = (const float*)d_in[10];
    const float* fc1_b = (const float*)d_in[11];
    const float* fc2_w = (const float*)d_in[12];
    const float* fc2_b = (const float*)d_in[13];
    const float* ln1_g = (const float*)d_in[14];
    const float* ln1_b = (const float*)d_in[15];
    const float* ln2_g = (const float*)d_in[16];
    const float* ln2_b = (const float*)d_in[17];
    float* out = (float*)d_out;

    char* ws = (char*)d_ws;
    const size_t M1 = 1048576;
    const size_t MB = 1048576;
    u16* Wc    = (u16*)ws;
    u16* wqc   = Wc;                       // [3072][1024] fused qkv rows
    u16* woc   = Wc + 3 * M1;
    u16* f1c   = Wc + 4 * M1;
    u16* f2c   = Wc + 8 * M1;
    u16* h     = (u16*)(ws + 24 * MB);
    u16* ctx   = h;
    u16* qkv   = (u16*)(ws + 32 * MB);
    u16* vT    = (u16*)(ws + 56 * MB);
    u16* ffh   = (u16*)(ws + 32 * MB);
    float* x1  = (float*)(ws + 64 * MB);
    float* qkvb = x1;                      // 3072 fp32, dead before x1 written
    u16* h2    = h;

    const dim3 blk(256);

    static bool s_attr_done = false;
    if (!s_attr_done) {
        hipFuncSetAttribute(reinterpret_cast<const void*>(gemm256_kernel),
                            hipFuncAttributeMaxDynamicSharedMemorySize, 131072);
        hipFuncSetAttribute(reinterpret_cast<const void*>(gemm128sq_kernel),
                            hipFuncAttributeMaxDynamicSharedMemorySize, 131072);
        s_attr_done = true;
    }

    // 0. weights fp32 -> bf16 (+ fused qkv bias)
    conv_w_kernel<<<12288, 256, 0, stream>>>(wq_w, wk_w, wv_w, wo_w, fc1_w, fc2_w,
                                             wq_b, wk_b, wv_b, qkvb, Wc);
    // 1. h = LN1(x)
    ln_kernel<<<4096, 64, 0, stream>>>(x, ln1_g, ln1_b, h);
    // 2. qkv = h @ [Wq;Wk;Wv]^T + b   (fused, N=3072) — 256^2 v4 m201-anatomy
    gemm256_kernel<<<dim3(16 * 12), dim3(512), 131072, stream>>>(
        h, wqc, qkvb, qkv, 4096, 3072, 1024, 0);
    // 3. vT = per-head transpose of V
    transp_v<<<dim3(32, 32), blk, 0, stream>>>(qkv, vT);
    // 4. ctx = causal_attn(q,k,vT)   (swizzled, double-buffered)
    attn_kernel<<<dim3(16, 32), blk, 0, stream>>>(qkv, vT, ctx);
    // 5. x1 = x + ctx @ Wo^T + bo    (fp32 out, 128x128 deep pipeline)
    gemm128sq_kernel<<<dim3(32, 8), blk, 131072, stream>>>(
        ctx, woc, wo_b, x, x1, 4096, 1024, 1024);
    // 6. h2 = LN2(x1)
    ln_kernel<<<4096, 64, 0, stream>>>(x1, ln2_g, ln2_b, h2);
    // 7. ffh = gelu(h2 @ fc1^T + b1) — 256^2 v4 m201-anatomy
    gemm256_kernel<<<dim3(16 * 16), dim3(512), 131072, stream>>>(
        h2, f1c, fc1_b, ffh, 4096, 4096, 1024, 1);
    // 8. out = x1 + ffh @ fc2^T + b2 (fp32 out, 128x128 deep pipeline)
    gemm128sq_kernel<<<dim3(32, 8), blk, 131072, stream>>>(
        ffh, f2c, fc2_b, x1, out, 4096, 1024, 4096);
}

// Round 9
// 350.524 us; speedup vs baseline: 1.2400x; 1.0055x over previous
//
#include <hip/hip_runtime.h>
#include <stdint.h>

typedef unsigned short u16;
typedef __bf16 bf16x8 __attribute__((ext_vector_type(8)));
typedef float floatx4 __attribute__((ext_vector_type(4)));

#define AS1(p) ((__attribute__((address_space(1))) void*)(void*)(p))
#define AS3(p) ((__attribute__((address_space(3))) void*)(p))

__device__ __forceinline__ u16 f2bf(float f) {
    unsigned u;
    __builtin_memcpy(&u, &f, 4);
    u += 0x7FFF + ((u >> 16) & 1);   // RNE
    return (u16)(u >> 16);
}
__device__ __forceinline__ u16 f2bf_trunc(float f) {
    unsigned u;
    __builtin_memcpy(&u, &f, 4);
    return (u16)(u >> 16);
}
__device__ __forceinline__ float exp2_fast(float x) {
    return __builtin_amdgcn_exp2f(x);    // v_exp_f32
}
__device__ __forceinline__ float gelu_f(float x) {
    return 0.5f * x * (1.0f + erff(x * 0.70710678118654752f));
}

// ---------------------------------------------------------------------------
// Convert the 6 weight matrices fp32 -> bf16 into ws (layout: wq wk wv wo f1 f2)
// ---------------------------------------------------------------------------
__global__ __launch_bounds__(256) void conv_w_kernel(
    const float* __restrict__ wq, const float* __restrict__ wk,
    const float* __restrict__ wv, const float* __restrict__ wo,
    const float* __restrict__ f1, const float* __restrict__ f2,
    const float* __restrict__ bq, const float* __restrict__ bk,
    const float* __restrict__ bv, float* __restrict__ qkvb,
    u16* __restrict__ W) {
    const size_t i4 = ((size_t)blockIdx.x * 256 + threadIdx.x) * 4;
    const size_t M1 = 1048576;
    const float* src;
    size_t off;
    if (i4 < M1)            { src = wq; off = i4; }
    else if (i4 < 2 * M1)   { src = wk; off = i4 - M1; }
    else if (i4 < 3 * M1)   { src = wv; off = i4 - 2 * M1; }
    else if (i4 < 4 * M1)   { src = wo; off = i4 - 3 * M1; }
    else if (i4 < 8 * M1)   { src = f1; off = i4 - 4 * M1; }
    else                    { src = f2; off = i4 - 8 * M1; }
    float4 d = *(const float4*)(src + off);
    ushort4 o;
    o.x = f2bf(d.x); o.y = f2bf(d.y); o.z = f2bf(d.z); o.w = f2bf(d.w);
    *(ushort4*)(W + i4) = o;
    if (blockIdx.x == 0) {
        for (int i = threadIdx.x; i < 1024; i += 256) {
            qkvb[i] = bq[i];
            qkvb[1024 + i] = bk[i];
            qkvb[2048 + i] = bv[i];
        }
    }
}

// ---------------------------------------------------------------------------
// LayerNorm: one wave per token row (D=1024 -> 16 elems/lane). fp32 in, bf16 out.
// ---------------------------------------------------------------------------
__global__ __launch_bounds__(64) void ln_kernel(const float* __restrict__ X,
                                                const float* __restrict__ G,
                                                const float* __restrict__ Bt,
                                                u16* __restrict__ Y) {
    const int row = blockIdx.x;
    const int lane = threadIdx.x;
    const float* xr = X + (size_t)row * 1024;
    float v[16];
    float s = 0.f;
#pragma unroll
    for (int i = 0; i < 16; ++i) { v[i] = xr[lane + i * 64]; s += v[i]; }
#pragma unroll
    for (int off = 1; off < 64; off <<= 1) s += __shfl_xor(s, off, 64);
    const float mu = s * (1.0f / 1024.0f);
    float ss = 0.f;
#pragma unroll
    for (int i = 0; i < 16; ++i) { float d = v[i] - mu; ss += d * d; }
#pragma unroll
    for (int off = 1; off < 64; off <<= 1) ss += __shfl_xor(ss, off, 64);
    const float rstd = rsqrtf(ss * (1.0f / 1024.0f) + 1e-5f);
    u16* yr = Y + (size_t)row * 1024;
#pragma unroll
    for (int i = 0; i < 16; ++i) {
        int c = lane + i * 64;
        yr[c] = f2bf((v[i] - mu) * rstd * G[c] + Bt[c]);
    }
}

// ---------------------------------------------------------------------------
// gemm128sq v5: 128x128 tile, 4 waves, BK=64, 4-buffer stage-3-ahead LDS
// pipeline, T2 XOR-swizzle, setprio. v5: NO explicit lgkmcnt/sched_barrier —
// ds_read->MFMA waits are compiler-managed partial drains (m141 lesson:
// order-pinning defeats hipcc's own fine-grained scheduling).
// fp32 out = A@Bt^T + bias + resid. Grid (M/128, N/128). 128 KiB dyn LDS.
// ---------------------------------------------------------------------------
__global__ __launch_bounds__(256, 1) void gemm128sq_kernel(
    const u16* __restrict__ A, const u16* __restrict__ Bt,
    const float* __restrict__ bias, const float* __restrict__ resid,
    float* __restrict__ C, int M, int N, int K) {
    extern __shared__ __align__(16) u16 smem[];   // 4 bufs x (A 8192 + B 8192) u16
    const int tid = threadIdx.x;
    const int wave = tid >> 6, lane = tid & 63;
    const int wm = (wave >> 1) * 64;
    const int wn = (wave & 1) * 64;
    const int lr = lane & 15, lk8 = (lane >> 4) * 8;
    const int r0 = (lane >> 4) * 4;
    const int m0 = blockIdx.x * 128, n0 = blockIdx.y * 128;
    const int NT = K >> 6;                        // 16 or 64
    const u16* const Ab = A + (size_t)m0 * K;
    const u16* const Bb = Bt + (size_t)n0 * K;

    const int srow = tid >> 3;                    // 0..31
    const int scol = 8 * ((tid & 7) ^ (srow & 7));
    const int sdst = tid * 8;                     // u16 offset within 2048-u16 chunk
    const int swz = (lr & 7) << 3;
    const int c0 = lk8 ^ swz;
    const int c1 = (32 + lk8) ^ swz;

    floatx4 acc[4][4];
#pragma unroll
    for (int i = 0; i < 4; ++i)
#pragma unroll
        for (int j = 0; j < 4; ++j) acc[i][j] = floatx4{0.f, 0.f, 0.f, 0.f};
    bf16x8 aF[4][2], bF[4][2];

#define STG(Tt)                                                                \
    {                                                                          \
        u16* const buf = smem + ((Tt) & 3) * 16384;                            \
        _Pragma("unroll")                                                      \
        for (int l = 0; l < 4; ++l) {                                          \
            const u16* srcA = Ab + (size_t)(l * 32 + srow) * K +               \
                              (size_t)(Tt) * 64 + scol;                        \
            __builtin_amdgcn_global_load_lds(                                  \
                AS1(srcA), AS3(buf + l * 2048 + sdst), 16, 0, 0);              \
        }                                                                      \
        _Pragma("unroll")                                                      \
        for (int l = 0; l < 4; ++l) {                                          \
            const u16* srcB = Bb + (size_t)(l * 32 + srow) * K +               \
                              (size_t)(Tt) * 64 + scol;                        \
            __builtin_amdgcn_global_load_lds(                                  \
                AS1(srcB), AS3(buf + 8192 + l * 2048 + sdst), 16, 0, 0);       \
        }                                                                      \
    }

    STG(0); STG(1); STG(2);
    for (int T = 0; T < NT; ++T) {
        const int rem = NT - 1 - T;
        if (rem >= 2)      asm volatile("s_waitcnt vmcnt(16)" ::: "memory");
        else if (rem == 1) asm volatile("s_waitcnt vmcnt(8)" ::: "memory");
        else               asm volatile("s_waitcnt vmcnt(0)" ::: "memory");
        asm volatile("s_barrier" ::: "memory");
        if (T + 3 < NT) STG(T + 3);
        const u16* const bufA = smem + (T & 3) * 16384;
        const u16* const bufB = bufA + 8192;
#pragma unroll
        for (int i = 0; i < 4; ++i) {
            aF[i][0] = *(const bf16x8*)&bufA[(wm + i * 16 + lr) * 64 + c0];
            aF[i][1] = *(const bf16x8*)&bufA[(wm + i * 16 + lr) * 64 + c1];
        }
#pragma unroll
        for (int j = 0; j < 4; ++j) {
            bF[j][0] = *(const bf16x8*)&bufB[(wn + j * 16 + lr) * 64 + c0];
            bF[j][1] = *(const bf16x8*)&bufB[(wn + j * 16 + lr) * 64 + c1];
        }
        // v5: no explicit lgkm wait / sched_barrier — compiler inserts
        // fine-grained lgkmcnt before each dependent MFMA.
        __builtin_amdgcn_s_setprio(1);
#pragma unroll
        for (int i = 0; i < 4; ++i)
#pragma unroll
            for (int j = 0; j < 4; ++j)
#pragma unroll
                for (int kk = 0; kk < 2; ++kk)
                    acc[i][j] = __builtin_amdgcn_mfma_f32_16x16x32_bf16(
                        aF[i][kk], bF[j][kk], acc[i][j], 0, 0, 0);
        __builtin_amdgcn_s_setprio(0);
    }
#undef STG

    // epilogue: fp32 out = acc + bias + resid
#pragma unroll
    for (int i = 0; i < 4; ++i)
#pragma unroll
        for (int j = 0; j < 4; ++j) {
            const int col = n0 + wn + j * 16 + lr;
            const float bv = bias[col];
#pragma unroll
            for (int r = 0; r < 4; ++r) {
                const int row = m0 + wm + i * 16 + r0 + r;
                C[(size_t)row * N + col] =
                    acc[i][j][r] + bv + resid[(size_t)row * N + col];
            }
        }
}

// ---------------------------------------------------------------------------
// gemm256 v5: v4's window anatomy (4 phases, barrier-isolated MFMA clusters,
// 1 half-tile stage per phase, single counted vmcnt(4) per window) MINUS the
// LGKM0 pins: no asm lgkmcnt(0), no sched_barrier(0). ds_read->MFMA ordering
// is data-dependency-tracked by the compiler (emits partial lgkmcnt drains).
// m141 lesson: explicit order-pinning collapsed 874->510 TF on m97; every
// ~600 TF variant here carried the same pins.
// Race-safety unchanged: every ds_read's result is consumed by an MFMA
// BEFORE the phase-end barrier, so its compiler-wait precedes the barrier;
// the vmcnt asm (compiler can't track global_load_lds->LDS) is kept.
// ---------------------------------------------------------------------------
__global__ __launch_bounds__(512, 2) void gemm256_kernel(
    const u16* __restrict__ A, const u16* __restrict__ Bt,
    const float* __restrict__ bias, u16* __restrict__ C,
    int M, int N, int K, int act) {
    extern __shared__ __align__(16) u16 smem[];
    u16* const lA = smem;          // [2][256*64] = 64 KiB
    u16* const lB = smem + 32768;  // [2][256*64] = 64 KiB
    const int tid = threadIdx.x;
    const int wave = tid >> 6, lane = tid & 63;
    const int wm = (wave >> 2) * 128;        // wave M-origin (0/128)
    const int wn = (wave & 3) * 64;          // wave N-origin (0/64/128/192)
    const int lr = lane & 15, lk8 = (lane >> 4) * 8;
    const int r0 = (lane >> 4) * 4;

    const int gM = M >> 8;
    int bid = blockIdx.x;
    { const int nwg = gridDim.x;
      const int q = nwg >> 3, r = nwg & 7, xcd = bid & 7, lid = bid >> 3;
      bid = (xcd < r ? xcd * (q + 1) : r * (q + 1) + (xcd - r) * q) + lid; }
    const int m0 = (bid % gM) << 8;
    const int n0 = (bid / gM) << 8;

    const int NT = K >> 6;                   // 16 here (even, >=4)
    const u16* const Ab = A + (size_t)m0 * K;
    const u16* const Bb = Bt + (size_t)n0 * K;

    const int srow = tid >> 3;                         // 0..63
    const int scol = 8 * ((tid & 7) ^ (srow & 7));     // element col, inv-swizzled
    const int sdst = tid * 8;                          // u16 offset (lane*16 B)
    const int swz = (lr & 7) << 3;
    const int c0 = lk8 ^ swz;                          // kk=0 frag col
    const int c1 = (32 + lk8) ^ swz;                   // kk=1 frag col

    floatx4 acc[8][4];
#pragma unroll
    for (int i = 0; i < 8; ++i)
#pragma unroll
        for (int j = 0; j < 4; ++j) acc[i][j] = floatx4{0.f, 0.f, 0.f, 0.f};
    bf16x8 aF[4][2];      // current mq half only (overwritten at ph3)
    bf16x8 bF[4][2];      // [nf][kk]

#define STAGE_HT(ldsbuf, gbase, h, Tt)                                         \
    {                                                                          \
        _Pragma("unroll")                                                      \
        for (int l = 0; l < 2; ++l) {                                          \
            const u16* src = (gbase) + (size_t)((h) * 128 + l * 64 + srow) * K \
                             + (size_t)(Tt) * 64 + scol;                       \
            __builtin_amdgcn_global_load_lds(                                  \
                AS1(src), AS3((ldsbuf) + (h) * 8192 + l * 4096 + sdst), 16, 0, 0); \
        }                                                                      \
    }
#define PH_BAR() asm volatile("s_barrier" ::: "memory")
#define RD_A(lAp, mq)                                                          \
    _Pragma("unroll")                                                          \
    for (int i = 0; i < 4; ++i) {                                              \
        aF[i][0] = *(const bf16x8*)&(lAp)[(wm + (mq) * 64 + i * 16 + lr) * 64 + c0]; \
        aF[i][1] = *(const bf16x8*)&(lAp)[(wm + (mq) * 64 + i * 16 + lr) * 64 + c1]; \
    }
#define RD_B2(lBp, nf0)                                                        \
    _Pragma("unroll")                                                          \
    for (int j = 0; j < 2; ++j) {                                              \
        bF[(nf0) + j][0] = *(const bf16x8*)&(lBp)[(wn + ((nf0) + j) * 16 + lr) * 64 + c0]; \
        bF[(nf0) + j][1] = *(const bf16x8*)&(lBp)[(wn + ((nf0) + j) * 16 + lr) * 64 + c1]; \
    }
#define MFMA_Q(mq, nq)                                                         \
    __builtin_amdgcn_s_setprio(1);                                             \
    _Pragma("unroll")                                                          \
    for (int i = 0; i < 4; ++i)                                                \
        _Pragma("unroll")                                                      \
        for (int j = 0; j < 2; ++j)                                            \
            _Pragma("unroll")                                                  \
            for (int kk = 0; kk < 2; ++kk)                                     \
                acc[(mq) * 4 + i][(nq) * 2 + j] =                              \
                    __builtin_amdgcn_mfma_f32_16x16x32_bf16(                   \
                        aF[i][kk], bF[(nq) * 2 + j][kk],                       \
                        acc[(mq) * 4 + i][(nq) * 2 + j], 0, 0, 0);             \
    __builtin_amdgcn_s_setprio(0);

#define WINDOW(P, T)                                                           \
    {                                                                          \
        u16* const lAp = lA + (P) * 16384;                                     \
        u16* const lBp = lB + (P) * 16384;                                     \
        u16* const lAn = lA + ((P) ^ 1) * 16384;                               \
        /* ph1: reads for Q(0,0); stage A(T+1)h0 */                            \
        RD_A(lAp, 0);                                                          \
        RD_B2(lBp, 0);                                                         \
        if ((T) + 1 < NT) STAGE_HT(lAn, Ab, 0, (T) + 1);                       \
        PH_BAR();                                                              \
        MFMA_Q(0, 0);                                                          \
        PH_BAR();                                                              \
        /* ph2: reads for Q(0,1); stage A(T+1)h1 */                            \
        RD_B2(lBp, 2);                                                         \
        if ((T) + 1 < NT) STAGE_HT(lAn, Ab, 1, (T) + 1);                       \
        PH_BAR();                                                              \
        MFMA_Q(0, 1);                                                          \
        PH_BAR();                                                              \
        /* ph3: reads for Q(1,0); stage B(T+2)h0 (B(T) reads retired @ph2) */  \
        RD_A(lAp, 1);                                                          \
        if ((T) + 2 < NT) STAGE_HT(lBp, Bb, 0, (T) + 2);                       \
        PH_BAR();                                                              \
        MFMA_Q(1, 0);                                                          \
        PH_BAR();                                                              \
        /* ph4: stage B(T+2)h1; MFMA Q(1,1); counted vmcnt; BAR */             \
        if ((T) + 2 < NT) STAGE_HT(lBp, Bb, 1, (T) + 2);                       \
        MFMA_Q(1, 1);                                                          \
        if ((T) + 2 < NT) asm volatile("s_waitcnt vmcnt(4)" ::: "memory");     \
        else              asm volatile("s_waitcnt vmcnt(0)" ::: "memory");     \
        PH_BAR();                                                              \
    }

    // prologue: A0,B0 (8 loads) + B1 (4 loads); keep B1 in flight
    STAGE_HT(lA, Ab, 0, 0);
    STAGE_HT(lA, Ab, 1, 0);
    STAGE_HT(lB, Bb, 0, 0);
    STAGE_HT(lB, Bb, 1, 0);
    if (NT > 1) {
        STAGE_HT(lB + 16384, Bb, 0, 1);
        STAGE_HT(lB + 16384, Bb, 1, 1);
    }
    asm volatile("s_waitcnt vmcnt(4)" ::: "memory");
    PH_BAR();

    for (int T = 0; T < NT; T += 2) {
        WINDOW(0, T);
        WINDOW(1, T + 1);
    }
#undef WINDOW
#undef MFMA_Q
#undef RD_B2
#undef RD_A
#undef PH_BAR
#undef STAGE_HT

    // epilogue: bias (+gelu) -> bf16
#pragma unroll
    for (int mq = 0; mq < 2; ++mq)
#pragma unroll
        for (int i = 0; i < 4; ++i)
#pragma unroll
            for (int nf = 0; nf < 4; ++nf) {
                const int col = n0 + wn + nf * 16 + lr;
                const float bv = bias[col];
                floatx4 v = acc[mq * 4 + i][nf];
#pragma unroll
                for (int r = 0; r < 4; ++r) {
                    const int row = m0 + wm + mq * 64 + i * 16 + r0 + r;
                    float x = v[r] + bv;
                    if (act) x = gelu_f(x);
                    C[(size_t)row * N + col] = f2bf(x);
                }
            }
}

// ---------------------------------------------------------------------------
// Transpose the V columns of qkv [4096][3072] into vT [32*64][2048]
// ---------------------------------------------------------------------------
__global__ __launch_bounds__(256) void transp_v(const u16* __restrict__ qkv,
                                                u16* __restrict__ vT) {
    __shared__ u16 lT[64 * 64];
    const int bh = blockIdx.x, tt = blockIdx.y;
    const int b = bh >> 4, h = bh & 15;
    const int t0 = tt * 64;
    const int tid = threadIdx.x;
    const int srow = tid >> 3, scol = (tid & 7) * 8;
#pragma unroll
    for (int rr = 0; rr < 2; ++rr) {
        const int row = srow + rr * 32;  // t-local
        uint4 d4 = *(const uint4*)(qkv + (size_t)(b * 2048 + t0 + row) * 3072 +
                                   2048 + h * 64 + scol);
        const u16* e = (const u16*)&d4;
#pragma unroll
        for (int t = 0; t < 8; ++t) lT[(scol + t) * 64 + row] = e[t];
    }
    __syncthreads();
#pragma unroll
    for (int rr = 0; rr < 2; ++rr) {
        const int row = srow + rr * 32;  // d index
        uint4 d4 = *(const uint4*)&lT[row * 64 + scol];
        *(uint4*)(vT + (size_t)(bh * 64 + row) * 2048 + t0 + scol) = d4;
    }
}

// ---------------------------------------------------------------------------
// Causal flash attention v6: merged pair + max-free softmax + T2 XOR-swizzle
// on all K/V/P LDS paths + double-buffered K/V with counted vmcnt(4) +
// setprio around MFMA clusters.
// ---------------------------------------------------------------------------
__global__ __launch_bounds__(256) void attn_kernel(const u16* __restrict__ qkv,
                                                   const u16* __restrict__ vT,
                                                   u16* __restrict__ O) {
    __shared__ __align__(16) u16 lK[2][64 * 64];     // [buf][key][dh]  16 KiB
    __shared__ __align__(16) u16 lV[2][64 * 64];     // [buf][dh][key]  16 KiB
    __shared__ __align__(16) u16 lP[4][16 * 64];     // per-wave P       8 KiB
    const int tid = threadIdx.x;
    const int wave = tid >> 6, lane = tid & 63;
    const int lr = lane & 15, khi = lane >> 4, lk8 = khi * 8;
    const int p = blockIdx.x;                        // 0..15; qa=31-p first
    const int bh = blockIdx.y;
    const int b = bh >> 4, hh = bh & 15;
    const int rb = b * 2048;
    const size_t vbase = (size_t)(bh * 64) * 2048;
    const int srow = tid >> 3, scol = 8 * ((tid & 7) ^ ((tid >> 3) & 7));
    const int sdst = tid * 8;
    const int r0 = khi * 4;
    const int qa = 31 - p, qb = p;
    const int qa0 = qa * 64, qb0 = qb * 64;
    const float C = 0.125f * 1.44269504088896f;      // scale * log2(e)

    const int swz = (lr & 7) << 3;
    const int cc0 = lk8 ^ swz;
    const int cc1 = (32 + lk8) ^ swz;

    // Q A-fragments for both tiles (direct from global; no LDS)
    bf16x8 aqA0, aqA1, aqB0, aqB1;
    {
        const size_t qoffA = (size_t)(rb + qa0 + wave * 16 + lr) * 3072 + hh * 64;
        aqA0 = *(const bf16x8*)(qkv + qoffA + lk8);
        aqA1 = *(const bf16x8*)(qkv + qoffA + 32 + lk8);
        const size_t qoffB = (size_t)(rb + qb0 + wave * 16 + lr) * 3072 + hh * 64;
        aqB0 = *(const bf16x8*)(qkv + qoffB + lk8);
        aqB1 = *(const bf16x8*)(qkv + qoffB + 32 + lk8);
    }

    floatx4 oA[4], oB[4];
    float lA_[4], lB_[4];                            // per-lane partial sums
#pragma unroll
    for (int r = 0; r < 4; ++r) {
        oA[r] = floatx4{0.f, 0.f, 0.f, 0.f};
        oB[r] = floatx4{0.f, 0.f, 0.f, 0.f};
        lA_[r] = 0.f; lB_[r] = 0.f;
    }

#define ASTAGE(Pb, kt_)                                                        \
    {                                                                          \
        const int k0_ = (kt_) * 64;                                            \
        _Pragma("unroll")                                                      \
        for (int rr = 0; rr < 2; ++rr) {                                       \
            const int row = srow + rr * 32;                                    \
            __builtin_amdgcn_global_load_lds(                                  \
                AS1(qkv + (size_t)(rb + k0_ + row) * 3072 + 1024 + hh * 64 + scol), \
                AS3(lK[Pb] + rr * 2048 + sdst), 16, 0, 0);                     \
            __builtin_amdgcn_global_load_lds(                                  \
                AS1(vT + vbase + (size_t)row * 2048 + k0_ + scol),             \
                AS3(lV[Pb] + rr * 2048 + sdst), 16, 0, 0);                     \
        }                                                                      \
    }

    // One QK->exp->PV round for one tile against the staged k-tile (buf Pb).
#define TILE_ROUND(Pb, aq0_, aq1_, oo_, ll_, q0_, diag_, k0_)                   \
    {                                                                           \
        float s[4][4];                                                          \
        __builtin_amdgcn_s_setprio(1);                                          \
        _Pragma("unroll")                                                       \
        for (int j = 0; j < 4; ++j) {                                           \
            bf16x8 bk0 = *(const bf16x8*)&lK[Pb][(j * 16 + lr) * 64 + cc0];     \
            bf16x8 bk1 = *(const bf16x8*)&lK[Pb][(j * 16 + lr) * 64 + cc1];     \
            floatx4 t = floatx4{0.f, 0.f, 0.f, 0.f};                            \
            t = __builtin_amdgcn_mfma_f32_16x16x32_bf16(aq0_, bk0, t, 0, 0, 0); \
            t = __builtin_amdgcn_mfma_f32_16x16x32_bf16(aq1_, bk1, t, 0, 0, 0); \
            _Pragma("unroll")                                                   \
            for (int r = 0; r < 4; ++r) s[j][r] = t[r];                         \
        }                                                                       \
        __builtin_amdgcn_s_setprio(0);                                          \
        if (diag_) {                                                            \
            _Pragma("unroll")                                                   \
            for (int j = 0; j < 4; ++j)                                         \
                _Pragma("unroll")                                               \
                for (int r = 0; r < 4; ++r)                                     \
                    if ((k0_) + j * 16 + lr > (q0_) + wave * 16 + r0 + r)       \
                        s[j][r] = -1e30f;                                       \
        }                                                                       \
        _Pragma("unroll")                                                       \
        for (int j = 0; j < 4; ++j)                                             \
            _Pragma("unroll")                                                   \
            for (int r = 0; r < 4; ++r) {                                       \
                float pv = exp2_fast(s[j][r] * C);                              \
                ll_[r] += pv;                                                   \
                lP[wave][(r0 + r) * 64 +                                        \
                         ((j * 16 + lr) ^ (((r0 + r) & 7) << 3))] =             \
                    f2bf_trunc(pv);                                             \
            }                                                                   \
        bf16x8 ap0 = *(const bf16x8*)&lP[wave][lr * 64 + cc0];                  \
        bf16x8 ap1 = *(const bf16x8*)&lP[wave][lr * 64 + cc1];                  \
        __builtin_amdgcn_s_setprio(1);                                          \
        _Pragma("unroll")                                                       \
        for (int jd = 0; jd < 4; ++jd) {                                        \
            bf16x8 bv0 = *(const bf16x8*)&lV[Pb][(jd * 16 + lr) * 64 + cc0];    \
            bf16x8 bv1 = *(const bf16x8*)&lV[Pb][(jd * 16 + lr) * 64 + cc1];    \
            oo_[jd] = __builtin_amdgcn_mfma_f32_16x16x32_bf16(ap0, bv0, oo_[jd], 0, 0, 0); \
            oo_[jd] = __builtin_amdgcn_mfma_f32_16x16x32_bf16(ap1, bv1, oo_[jd], 0, 0, 0); \
        }                                                                       \
        __builtin_amdgcn_s_setprio(0);                                          \
    }

    ASTAGE(0, 0);
    for (int kt = 0; kt <= qa; ++kt) {
        const int P = kt & 1;
        const int k0 = kt * 64;
        if (kt < qa) {
            ASTAGE(P ^ 1, kt + 1);
            asm volatile("s_waitcnt vmcnt(4)" ::: "memory");
        } else {
            asm volatile("s_waitcnt vmcnt(0)" ::: "memory");
        }
        asm volatile("s_barrier" ::: "memory");

        TILE_ROUND(P, aqA0, aqA1, oA, lA_, qa0, kt == qa, k0);
        if (kt <= qb)
            TILE_ROUND(P, aqB0, aqB1, oB, lB_, qb0, kt == qb, k0);

        asm volatile("s_barrier" ::: "memory");  // retire buf-P reads before restage
    }
#undef TILE_ROUND
#undef ASTAGE

    // one-time denominator reduce over the 16 lanes sharing khi (lr bits)
#pragma unroll
    for (int off = 1; off < 16; off <<= 1)
#pragma unroll
        for (int r = 0; r < 4; ++r) {
            lA_[r] += __shfl_xor(lA_[r], off, 64);
            lB_[r] += __shfl_xor(lB_[r], off, 64);
        }

    // normalize + store ctx for both tiles (lane's rows are khi*4+r)
#pragma unroll
    for (int r = 0; r < 4; ++r) {
        const float invA = 1.0f / lA_[r];
        const float invB = 1.0f / lB_[r];
#pragma unroll
        for (int jd = 0; jd < 4; ++jd) {
            const size_t offA = (size_t)(rb + qa0 + wave * 16 + r0 + r) * 1024 +
                                hh * 64 + jd * 16 + lr;
            O[offA] = f2bf(oA[jd][r] * invA);
            const size_t offB = (size_t)(rb + qb0 + wave * 16 + r0 + r) * 1024 +
                                hh * 64 + jd * 16 + lr;
            O[offB] = f2bf(oB[jd][r] * invB);
        }
    }
}

// ---------------------------------------------------------------------------
extern "C" void kernel_launch(void* const* d_in, const int* in_sizes, int n_in,
                              void* d_out, int out_size, void* d_ws, size_t ws_size,
                              hipStream_t stream) {
    const float* x     = (const float*)d_in[0];
    // d_in[1] = causal mask (deterministic, unused)
    const float* wq_w  = (const float*)d_in[2];
    const float* wq_b  = (const float*)d_in[3];
    const float* wk_w  = (const float*)d_in[4];
    const float* wk_b  = (const float*)d_in[5];
    const float* wv_w  = (const float*)d_in[6];
    const float* wv_b  = (const float*)d_in[7];
    const float* wo_w  = (const float*)d_in[8];
    const float* wo_b  = (const float*)d_in[9];
    const float* fc1_w = (const float*)d_in[10];
    const float* fc1_b = (const float*)d_in[11];
    const float* fc2_w = (const float*)d_in[12];
    const float* fc2_b = (const float*)d_in[13];
    const float* ln1_g = (const float*)d_in[14];
    const float* ln1_b = (const float*)d_in[15];
    const float* ln2_g = (const float*)d_in[16];
    const float* ln2_b = (const float*)d_in[17];
    float* out = (float*)d_out;

    char* ws = (char*)d_ws;
    const size_t M1 = 1048576;
    const size_t MB = 1048576;
    u16* Wc    = (u16*)ws;
    u16* wqc   = Wc;                       // [3072][1024] fused qkv rows
    u16* woc   = Wc + 3 * M1;
    u16* f1c   = Wc + 4 * M1;
    u16* f2c   = Wc + 8 * M1;
    u16* h     = (u16*)(ws + 24 * MB);
    u16* ctx   = h;
    u16* qkv   = (u16*)(ws + 32 * MB);
    u16* vT    = (u16*)(ws + 56 * MB);
    u16* ffh   = (u16*)(ws + 32 * MB);
    float* x1  = (float*)(ws + 64 * MB);
    float* qkvb = x1;                      // 3072 fp32, dead before x1 written
    u16* h2    = h;

    const dim3 blk(256);

    static bool s_attr_done = false;
    if (!s_attr_done) {
        hipFuncSetAttribute(reinterpret_cast<const void*>(gemm256_kernel),
                            hipFuncAttributeMaxDynamicSharedMemorySize, 131072);
        hipFuncSetAttribute(reinterpret_cast<const void*>(gemm128sq_kernel),
                            hipFuncAttributeMaxDynamicSharedMemorySize, 131072);
        s_attr_done = true;
    }

    // 0. weights fp32 -> bf16 (+ fused qkv bias)
    conv_w_kernel<<<12288, 256, 0, stream>>>(wq_w, wk_w, wv_w, wo_w, fc1_w, fc2_w,
                                             wq_b, wk_b, wv_b, qkvb, Wc);
    // 1. h = LN1(x)
    ln_kernel<<<4096, 64, 0, stream>>>(x, ln1_g, ln1_b, h);
    // 2. qkv = h @ [Wq;Wk;Wv]^T + b   (fused, N=3072) — 256^2 v5 unpinned
    gemm256_kernel<<<dim3(16 * 12), dim3(512), 131072, stream>>>(
        h, wqc, qkvb, qkv, 4096, 3072, 1024, 0);
    // 3. vT = per-head transpose of V
    transp_v<<<dim3(32, 32), blk, 0, stream>>>(qkv, vT);
    // 4. ctx = causal_attn(q,k,vT)   (swizzled, double-buffered)
    attn_kernel<<<dim3(16, 32), blk, 0, stream>>>(qkv, vT, ctx);
    // 5. x1 = x + ctx @ Wo^T + bo    (fp32 out, 128x128 v5 unpinned)
    gemm128sq_kernel<<<dim3(32, 8), blk, 131072, stream>>>(
        ctx, woc, wo_b, x, x1, 4096, 1024, 1024);
    // 6. h2 = LN2(x1)
    ln_kernel<<<4096, 64, 0, stream>>>(x1, ln2_g, ln2_b, h2);
    // 7. ffh = gelu(h2 @ fc1^T + b1) — 256^2 v5 unpinned
    gemm256_kernel<<<dim3(16 * 16), dim3(512), 131072, stream>>>(
        h2, f1c, fc1_b, ffh, 4096, 4096, 1024, 1);
    // 8. out = x1 + ffh @ fc2^T + b2 (fp32 out, 128x128 v5 unpinned)
    gemm128sq_kernel<<<dim3(32, 8), blk, 131072, stream>>>(
        ffh, f2c, fc2_b, x1, out, 4096, 1024, 4096);
}